// Round 13
// baseline (246.592 us; speedup 1.0000x reference)
//
#include <hip/hip_runtime.h>

namespace {
constexpr int T = 512;
constexpr int BATCH = 512;
constexpr int D = 32;
constexpr int H = 64;
constexpr int G3 = 192;
}

typedef float v2f __attribute__((ext_vector_type(2)));

__device__ __forceinline__ float rcpf(float x) { return __builtin_amdgcn_rcpf(x); }
__device__ __forceinline__ float sigm(float x) { return rcpf(1.0f + __expf(-x)); }
__device__ __forceinline__ float tanh_fast(float x) {
    return 1.0f - 2.0f * rcpf(__expf(2.0f * x) + 1.0f);
}
__device__ __forceinline__ void pk2(v2f& acc, v2f w, v2f v) {
    asm("v_pk_fma_f32 %0, %1, %2, %0" : "+v"(acc) : "v"(w), "v"(v));
}
__device__ __forceinline__ float quad_sum(float v) {
    int i = __builtin_bit_cast(int, v);
    float t = __builtin_bit_cast(float,
        __builtin_amdgcn_update_dpp(0, i, 0xB1, 0xF, 0xF, true)); // [1,0,3,2]
    v += t;
    i = __builtin_bit_cast(int, v);
    t = __builtin_bit_cast(float,
        __builtin_amdgcn_update_dpp(0, i, 0x4E, 0xF, 0xF, true)); // [2,3,0,1]
    return v + t;
}
// LDS-only barrier: drains lgkm (h_lds write) but leaves vmcnt loads (xp
// prefetch) in flight across the barrier — __syncthreads would drain them.
__device__ __forceinline__ void step_barrier() {
    asm volatile("s_waitcnt lgkmcnt(0)" ::: "memory");
    __builtin_amdgcn_s_barrier();
}

// ---------------- phase 1: xp[b][t][g] = sum_d x[b][t][d] * w_ih_f[g][d] ----
__global__ __launch_bounds__(G3) void xproj_kernel(
    const float* __restrict__ x, const float* __restrict__ w_ih_f,
    float* __restrict__ xp)
{
    const int bidx = blockIdx.x;      // 0..2047
    const int b = bidx >> 2;          // batch row
    const int c = bidx & 3;           // t-chunk of 128
    const int tid = threadIdx.x;      // 0..191 = gate-output g

    __shared__ float4 xs[128 * (D / 4)];   // 16 KB chunk of x

    {
        const float4* xg = reinterpret_cast<const float4*>(
            x + ((size_t)b * T + (size_t)c * 128) * D);
        for (int i = tid; i < 128 * (D / 4); i += G3) xs[i] = xg[i];
    }
    v2f w[16];
    {
        const v2f* wp = reinterpret_cast<const v2f*>(w_ih_f + (size_t)tid * D);
        #pragma unroll
        for (int m = 0; m < 16; ++m) w[m] = wp[m];
    }
    __syncthreads();

    float* xpo = xp + ((size_t)b * T + (size_t)c * 128) * G3 + tid;
    for (int tt = 0; tt < 128; ++tt) {
        const float4* xr = &xs[tt * (D / 4)];
        v2f acc = {0.f, 0.f};
        #pragma unroll
        for (int m = 0; m < D / 4; ++m) {
            float4 xv = xr[m];
            v2f lo = {xv.x, xv.y}, hi = {xv.z, xv.w};
            pk2(acc, w[2 * m], lo);
            pk2(acc, w[2 * m + 1], hi);
        }
        xpo[(size_t)tt * G3] = acc.x + acc.y;   // coalesced across g
    }
}

// ---------------- phase 2: recurrence (split-4, W_hh-only residency) --------
__global__ __launch_bounds__(256, 1) void gru_rec_kernel(
    const float* __restrict__ x, const float* __restrict__ xp,
    const float* __restrict__ w_hh_f,
    const float* __restrict__ b_ih_f, const float* __restrict__ b_hh_f,
    const float* __restrict__ w_ih_b, const float* __restrict__ b_ih_b,
    const float* __restrict__ b_hh_b,
    const float* __restrict__ fc1_w, const float* __restrict__ fc1_b,
    const float* __restrict__ fc2_w, const float* __restrict__ fc2_b,
    float* __restrict__ out)
{
    const int b   = blockIdx.x;
    const int tid = threadIdx.x;
    const int j   = tid >> 2;     // h-index, owns all 3 gates
    const int q   = tid & 3;      // K-split quarter (DPP quad lane)
    const int kh0 = q * 16;

    // 64 KB pad: keeps the compiler's occupancy model at 2 blocks/CU so the
    // VGPR grant stays generous (empirically 88-132 with big LDS vs 64 without).
    __shared__ float4 pad_lds[4096];
    __shared__ __align__(16) float h_lds[2][H];
    __shared__ float last_lds[2 * H];

    // data-dependent never-true touch so pad_lds can't be DCE'd
    if (x[0] > 3.0e38f) {
        pad_lds[tid] = make_float4(0.f, 0.f, 0.f, 0.f);
        __syncthreads();
        out[b] = pad_lds[(tid + 7) & 4095].x;
    }

    // W_hh slices only: 24 v2f = 48 VGPR
    v2f wr2[8], wz2[8], wn2[8];
    {
        const v2f* pr = reinterpret_cast<const v2f*>(w_hh_f + (size_t)j * H + kh0);
        const v2f* pz = reinterpret_cast<const v2f*>(w_hh_f + (size_t)(H + j) * H + kh0);
        const v2f* pn = reinterpret_cast<const v2f*>(w_hh_f + (size_t)(2 * H + j) * H + kh0);
        #pragma unroll
        for (int m = 0; m < 8; ++m) { wr2[m] = pr[m]; wz2[m] = pz[m]; wn2[m] = pn[m]; }
    }
    const float pre_r  = b_ih_f[j]         + b_hh_f[j];
    const float pre_z  = b_ih_f[H + j]     + b_hh_f[H + j];
    const float pre_nx = b_ih_f[2 * H + j];
    const float pre_nh = b_hh_f[2 * H + j];

    if (tid < H) h_lds[0][tid] = 0.0f;
    __syncthreads();

    const float* xpt = xp + (size_t)b * T * G3 + j;
    // prefetch xp for t=0 and t=1 (depth 2; rides vmcnt across step barriers)
    float a_r = xpt[0],   a_z = xpt[64],      a_n = xpt[128];
    float b_r = xpt[G3],  b_z = xpt[G3 + 64], b_n = xpt[G3 + 128];

    float hold = 0.0f;

    #define GRU_STEP(CUR, NXT, XR, XZ, XN, TNEXT)                              \
    {                                                                          \
        v2f hh[8];                                                             \
        {                                                                      \
            const v2f* hp = reinterpret_cast<const v2f*>(&h_lds[CUR][kh0]);    \
            _Pragma("unroll")                                                  \
            for (int m = 0; m < 8; ++m) hh[m] = hp[m];                         \
        }                                                                      \
        v2f pr = {0.f,0.f}, pz = {0.f,0.f}, nh = {0.f,0.f};                    \
        _Pragma("unroll")                                                      \
        for (int m = 0; m < 8; ++m) pk2(pr, wr2[m], hh[m]);                    \
        _Pragma("unroll")                                                      \
        for (int m = 0; m < 8; ++m) pk2(pz, wz2[m], hh[m]);                    \
        _Pragma("unroll")                                                      \
        for (int m = 0; m < 8; ++m) pk2(nh, wn2[m], hh[m]);                    \
        const float cr = XR, cz = XZ, cn = XN;                                 \
        { /* reload this slot for two steps ahead */                           \
            const float* p = xpt + (size_t)((TNEXT) & (T - 1)) * G3;           \
            XR = p[0]; XZ = p[64]; XN = p[128];                                \
        }                                                                      \
        const float vr  = quad_sum(pr.x + pr.y) + cr + pre_r;                  \
        const float vz  = quad_sum(pz.x + pz.y) + cz + pre_z;                  \
        const float vnh = quad_sum(nh.x + nh.y) + pre_nh;                      \
        const float r = sigm(vr);                                              \
        const float z = sigm(vz);                                              \
        const float n = tanh_fast(cn + pre_nx + r * vnh);                      \
        const float hnew = n + z * (hold - n);                                 \
        hold = hnew;                                                           \
        if (q == 0) h_lds[NXT][j] = hnew;                                      \
        step_barrier();                                                        \
    }

    for (int t = 0; t < T; t += 2) {
        GRU_STEP(0, 1, a_r, a_z, a_n, t + 2)   // even step
        GRU_STEP(1, 0, b_r, b_z, b_n, t + 3)   // odd step
    }
    #undef GRU_STEP

    // ---- epilogue ----
    const int wave = tid >> 6, lane = tid & 63;

    if (wave == 0) last_lds[lane] = h_lds[0][lane];   // t=511 wrote buffer 0

    if (wave == 1) {   // backward dir: ONE step from h0=0 on x[b][T-1][:]
        const float* xT = x + ((size_t)b * T + (T - 1)) * D;
        const int jj = lane;
        float xr = b_ih_b[jj];
        float xz = b_ih_b[H + jj];
        float xn = b_ih_b[2 * H + jj];
        #pragma unroll
        for (int k = 0; k < D; ++k) {
            const float xv = xT[k];
            xr = fmaf(w_ih_b[(size_t)jj * D + k],           xv, xr);
            xz = fmaf(w_ih_b[(size_t)(H + jj) * D + k],     xv, xz);
            xn = fmaf(w_ih_b[(size_t)(2 * H + jj) * D + k], xv, xn);
        }
        const float r = sigm(xr + b_hh_b[jj]);
        const float z = sigm(xz + b_hh_b[H + jj]);
        const float n = tanh_fast(xn + r * b_hh_b[2 * H + jj]);
        last_lds[H + jj] = (1.0f - z) * n;
    }
    __syncthreads();

    if (wave == 0) {
        float acc = fc1_b[lane];
        const float* w1 = fc1_w + (size_t)lane * (2 * H);
        #pragma unroll 8
        for (int c = 0; c < 2 * H; ++c) acc = fmaf(w1[c], last_lds[c], acc);
        acc = (acc >= 0.0f) ? acc : 0.2f * acc;
        float red = acc * fc2_w[lane];
        #pragma unroll
        for (int off = 32; off > 0; off >>= 1)
            red += __shfl_down(red, off);
        if (lane == 0) out[b] = red + fc2_b[0];
    }
}

extern "C" void kernel_launch(void* const* d_in, const int* in_sizes, int n_in,
                              void* d_out, int out_size, void* d_ws, size_t ws_size,
                              hipStream_t stream) {
    const float* x      = (const float*)d_in[0];
    const float* w_ih_f = (const float*)d_in[1];
    const float* w_hh_f = (const float*)d_in[2];
    const float* b_ih_f = (const float*)d_in[3];
    const float* b_hh_f = (const float*)d_in[4];
    const float* w_ih_b = (const float*)d_in[5];
    // d_in[6] = w_hh_b unused (backward dir runs one step from h0=0)
    const float* b_ih_b = (const float*)d_in[7];
    const float* b_hh_b = (const float*)d_in[8];
    const float* fc1_w  = (const float*)d_in[9];
    const float* fc1_b  = (const float*)d_in[10];
    const float* fc2_w  = (const float*)d_in[11];
    const float* fc2_b  = (const float*)d_in[12];
    float* out = (float*)d_out;

    // phase 1: xp = x @ W_ih^T into d_ws (201 MB)
    xproj_kernel<<<BATCH * 4, G3, 0, stream>>>(x, w_ih_f, (float*)d_ws);
    // phase 2: recurrence with W_hh-only register residency
    gru_rec_kernel<<<BATCH, 256, 0, stream>>>(
        x, (const float*)d_ws, w_hh_f, b_ih_f, b_hh_f,
        w_ih_b, b_ih_b, b_hh_b, fc1_w, fc1_b, fc2_w, fc2_b, out);
    (void)ws_size; (void)in_sizes; (void)n_in; (void)out_size;
}